// Round 5
// baseline (1331.209 us; speedup 1.0000x reference)
//
#include <hip/hip_runtime.h>

typedef unsigned short u16;
typedef __attribute__((ext_vector_type(8))) short bf16x8;
typedef __attribute__((ext_vector_type(4))) float f32x4;

#define B_ 4
#define D_ 1024
#define N_ 1024
#define H_ 16
#define DK_ 64

__device__ inline float bf2f(u16 x) {
    union { unsigned u; float f; } c; c.u = ((unsigned)x) << 16; return c.f;
}
__device__ inline u16 f2bf(float f) {
    union { float f; unsigned u; } c; c.f = f;
    unsigned r = c.u + 0x7fff + ((c.u >> 16) & 1);
    return (u16)(r >> 16);
}

#if __has_builtin(__builtin_amdgcn_exp2f)
#define EXP2(x) __builtin_amdgcn_exp2f(x)
#else
#define EXP2(x) __expf((x) * 0.6931471805599453f)
#endif

// fl=1 -> storage fp32 (convert on load), fl=0 -> bf16
__device__ inline bf16x8 load8(const void* p, size_t idx, int fl) {
    if (!fl) return *(const bf16x8*)((const u16*)p + idx);
    const float* fp = (const float*)p + idx;
    f32x4 a = *(const f32x4*)fp;
    f32x4 b = *(const f32x4*)(fp + 4);
    bf16x8 r;
    #pragma unroll
    for (int j = 0; j < 4; ++j) {
        ((u16*)&r)[j]     = f2bf(a[j]);
        ((u16*)&r)[4 + j] = f2bf(b[j]);
    }
    return r;
}

// fp32 -> bf16 bulk convert, 8 elems/thread
__global__ __launch_bounds__(256) void k_cvt(
    const float* __restrict__ src, u16* __restrict__ dst, int n8)
{
    int i = blockIdx.x * 256 + threadIdx.x;
    if (i < n8) {
        const f32x4* s = (const f32x4*)src;
        f32x4 a = s[2 * i], b = s[2 * i + 1];
        bf16x8 r;
        #pragma unroll
        for (int j = 0; j < 4; ++j) {
            ((u16*)&r)[j]     = f2bf(a[j]);
            ((u16*)&r)[4 + j] = f2bf(b[j]);
        }
        ((bf16x8*)dst)[i] = r;
    }
}

// Wm permute+convert: dst[n][h*64+dk] = bf16(src[n][dk*16+h]).
// Matches at-layout [b][pos][h*64+dk] so k_merged needs no changes.
__global__ __launch_bounds__(256) void k_cvtperm(
    const float* __restrict__ src, u16* __restrict__ dst)
{
    int i = blockIdx.x * 256 + threadIdx.x;   // 131072 = 1024 rows * 128 chunks
    int n = i >> 7, c8 = i & 127;
    int h = c8 >> 3, dkb = (c8 & 7) * 8;
    bf16x8 r;
    #pragma unroll
    for (int e = 0; e < 8; ++e)
        ((u16*)&r)[e] = f2bf(src[(size_t)n * 1024 + (size_t)(dkb + e) * 16 + h]);
    *(bf16x8*)&dst[(size_t)n * 1024 + h * 64 + dkb] = r;
}

// ---------------------------------------------------------------------------
// global_load_lds direct-to-LDS staging.
// ---------------------------------------------------------------------------
__device__ __forceinline__ void gload16(const u16* g, u16* l) {
    __builtin_amdgcn_global_load_lds(
        (const __attribute__((address_space(1))) void*)g,
        (__attribute__((address_space(3))) void*)l, 16, 0, 0);
}

template<int ROWS>
__device__ __forceinline__ void stage_rows(const u16* __restrict__ g, int ld,
                                           int k0, u16* L, int wave)
{
    #pragma unroll
    for (int i = 0; i < ROWS / 64; ++i)
        gload16(g + (size_t)(i * 64) * ld + k0, L + i * 2048 + wave * 512);
}

template<int N>
__device__ __forceinline__ void waitcnt_vm() {
    if constexpr (N == 0)      asm volatile("s_waitcnt vmcnt(0)" ::: "memory");
    else if constexpr (N == 3) asm volatile("s_waitcnt vmcnt(3)" ::: "memory");
    else if constexpr (N == 4) asm volatile("s_waitcnt vmcnt(4)" ::: "memory");
    else if constexpr (N == 6) asm volatile("s_waitcnt vmcnt(6)" ::: "memory");
    else if constexpr (N == 8) asm volatile("s_waitcnt vmcnt(8)" ::: "memory");
}

// ---------------------------------------------------------------------------
// bf16 GEMM core: 3 LDS buffers, 2-deep prefetch, counted vmcnt.
// ---------------------------------------------------------------------------
template<int MT, int NT>
__device__ inline void gemm_bf16(const u16* __restrict__ A, int lda,
                                 const u16* __restrict__ Bt, size_t eoff,
                                 int ldb, int K, int m0, int n0,
                                 u16* lds, f32x4 acc[MT/32][NT/32])
{
    constexpr int FM = MT / 32, FN = NT / 32;
    constexpr int TSZ = (MT + NT) * 32;
    constexpr int NL  = MT / 64 + NT / 64;
    const int tid  = threadIdx.x;
    const int wave = tid >> 6, lane = tid & 63;
    const int quad = lane >> 4, l15 = lane & 15;
    const int wm = (wave >> 1) * (MT / 2);
    const int wn = (wave & 1) * (NT / 2);

    const u16* ga = A + (size_t)(m0 + (tid >> 2)) * lda + ((tid & 3) << 3);
    const u16* gb = Bt + eoff + (size_t)(n0 + (tid >> 2)) * ldb + ((tid & 3) << 3);

    stage_rows<MT>(ga, lda, 0, lds, wave);
    stage_rows<NT>(gb, ldb, 0, lds + MT * 32, wave);
    if (K > 32) {
        stage_rows<MT>(ga, lda, 32, lds + TSZ, wave);
        stage_rows<NT>(gb, ldb, 32, lds + TSZ + MT * 32, wave);
    }

    int b0 = 0;
    for (int k0 = 0; k0 < K - 32; k0 += 32) {
        waitcnt_vm<NL>();
        __builtin_amdgcn_s_barrier();

        const u16* La = lds + b0 * TSZ;
        const u16* Lb = La + MT * 32;
        bf16x8 af[FM], bv[FN];
        #pragma unroll
        for (int f = 0; f < FM; ++f)
            af[f] = *(const bf16x8*)&La[(wm + f * 16 + l15) * 32 + quad * 8];
        #pragma unroll
        for (int f = 0; f < FN; ++f)
            bv[f] = *(const bf16x8*)&Lb[(wn + f * 16 + l15) * 32 + quad * 8];

        if (k0 + 64 < K) {
            int b2 = b0 + 2; if (b2 >= 3) b2 -= 3;
            u16* Nx = lds + b2 * TSZ;
            stage_rows<MT>(ga, lda, k0 + 64, Nx, wave);
            stage_rows<NT>(gb, ldb, k0 + 64, Nx + MT * 32, wave);
        }

        #pragma unroll
        for (int fm = 0; fm < FM; ++fm)
            #pragma unroll
            for (int fn = 0; fn < FN; ++fn)
                acc[fm][fn] = __builtin_amdgcn_mfma_f32_16x16x32_bf16(
                    af[fm], bv[fn], acc[fm][fn], 0, 0, 0);

        b0 = (b0 == 2) ? 0 : b0 + 1;
    }

    waitcnt_vm<0>();
    __builtin_amdgcn_s_barrier();
    {
        const u16* La = lds + b0 * TSZ;
        const u16* Lb = La + MT * 32;
        bf16x8 af[FM], bv[FN];
        #pragma unroll
        for (int f = 0; f < FM; ++f)
            af[f] = *(const bf16x8*)&La[(wm + f * 16 + l15) * 32 + quad * 8];
        #pragma unroll
        for (int f = 0; f < FN; ++f)
            bv[f] = *(const bf16x8*)&Lb[(wn + f * 16 + l15) * 32 + quad * 8];
        #pragma unroll
        for (int fm = 0; fm < FM; ++fm)
            #pragma unroll
            for (int fn = 0; fn < FN; ++fn)
                acc[fm][fn] = __builtin_amdgcn_mfma_f32_16x16x32_bf16(
                    af[fm], bv[fn], acc[fm][fn], 0, 0, 0);
    }
    __syncthreads();
}

// ---------------------------------------------------------------------------
// fp32-weight fallback core (mode 0 only): reg-staged, padded LDS.
// ---------------------------------------------------------------------------
template<int MT, int NT>
__device__ inline void gemm_core(const u16* __restrict__ A, int lda,
                                 const void* __restrict__ Bt, size_t eoff,
                                 int ldb, int fl,
                                 int K, int m0, int n0,
                                 u16* lds, f32x4 acc[MT/32][NT/32])
{
    constexpr int FM = MT / 32, FN = NT / 32;
    constexpr int CA = MT * 4 / 256, CB = NT * 4 / 256;
    const int tid  = threadIdx.x;
    const int wave = tid >> 6, lane = tid & 63;
    const int quad = lane >> 4, l15 = lane & 15;
    const int wm = (wave >> 1) * (MT / 2);
    const int wn = (wave & 1) * (NT / 2);

    int arow[CA], acol[CA], brow[CB], bcol[CB];
    #pragma unroll
    for (int i = 0; i < CA; ++i) { int x = tid + i * 256; arow[i] = x >> 2; acol[i] = (x & 3) << 3; }
    #pragma unroll
    for (int i = 0; i < CB; ++i) { int x = tid + i * 256; brow[i] = x >> 2; bcol[i] = (x & 3) << 3; }

    bf16x8 pa[CA], pb[CB];
    #pragma unroll
    for (int i = 0; i < CA; ++i)
        pa[i] = *(const bf16x8*)(A + (size_t)(m0 + arow[i]) * lda + acol[i]);
    #pragma unroll
    for (int i = 0; i < CB; ++i)
        pb[i] = load8(Bt, eoff + (size_t)(n0 + brow[i]) * ldb + bcol[i], fl);

    int buf = 0;
    for (int k0 = 0; k0 < K; k0 += 32) {
        u16* La = lds + buf * ((MT + NT) * 40);
        u16* Lb = La + MT * 40;
        #pragma unroll
        for (int i = 0; i < CA; ++i) *(bf16x8*)&La[arow[i] * 40 + acol[i]] = pa[i];
        #pragma unroll
        for (int i = 0; i < CB; ++i) *(bf16x8*)&Lb[brow[i] * 40 + bcol[i]] = pb[i];
        __syncthreads();

        if (k0 + 32 < K) {
            #pragma unroll
            for (int i = 0; i < CA; ++i)
                pa[i] = *(const bf16x8*)(A + (size_t)(m0 + arow[i]) * lda + k0 + 32 + acol[i]);
            #pragma unroll
            for (int i = 0; i < CB; ++i)
                pb[i] = load8(Bt, eoff + (size_t)(n0 + brow[i]) * ldb + k0 + 32 + bcol[i], fl);
        }

        bf16x8 af[FM], bv[FN];
        #pragma unroll
        for (int f = 0; f < FM; ++f)
            af[f] = *(bf16x8*)&La[(wm + f * 16 + l15) * 40 + quad * 8];
        #pragma unroll
        for (int f = 0; f < FN; ++f)
            bv[f] = *(bf16x8*)&Lb[(wn + f * 16 + l15) * 40 + quad * 8];
        #pragma unroll
        for (int fm = 0; fm < FM; ++fm)
            #pragma unroll
            for (int fn = 0; fn < FN; ++fn)
                acc[fm][fn] = __builtin_amdgcn_mfma_f32_16x16x32_bf16(
                    af[fm], bv[fn], acc[fm][fn], 0, 0, 0);
        buf ^= 1;
    }
}

#define EPI_SETUP \
    const int tid = threadIdx.x; \
    const int wave = tid >> 6, lane = tid & 63; \
    const int quad = lane >> 4, l15 = lane & 15;

__device__ __forceinline__ int swz(int off) {
    return off ^ (((off >> 10) & 7) << 3);
}

// ---------------------------------------------------------------------------
// K1: QKV. z = mat (0=q,1=k,2=v). A = xb [4096][1024].
// q -> [bh][dkc=dk>>3][pos][dk&7]    (2KB-contiguous per block per h)
// k -> FRAGMENT layout: [bh][g=pos>>4][kk=dk>>5][quad=(dk>>3)&3][l15=pos&15][j=dk&7]
// v -> FRAGMENT layout: [bh][c=pos>>5][fn=dk>>4][quad=(pos>>3)&3][l15=dk&15][j=pos&7]
// Epilogue: acc -> LDS (dest-order, swizzled) -> linear b128 reads ->
// dwordx4 global stores (full 64B lines).
// ---------------------------------------------------------------------------
__global__ __launch_bounds__(256) void k_qkv(
    const u16* __restrict__ xb,
    const void* __restrict__ Wq, const void* __restrict__ Wk, const void* __restrict__ Wv,
    const float* __restrict__ bq, const float* __restrict__ bk, const float* __restrict__ bv,
    int fl, u16* __restrict__ qh, u16* __restrict__ kh, u16* __restrict__ vt)
{
    __shared__ __align__(16) u16 lds[3 * (128 + 128) * 32];   // 48 KB
    int mat = blockIdx.z;
    const void* W     = mat == 0 ? Wq : (mat == 1 ? Wk : Wv);
    const float* bias = mat == 0 ? bq : (mat == 1 ? bk : bv);
    int m0 = blockIdx.x * 128, n0 = blockIdx.y * 128;

    f32x4 acc[4][4];
    #pragma unroll
    for (int i = 0; i < 4; ++i)
        #pragma unroll
        for (int j = 0; j < 4; ++j) acc[i][j] = f32x4{0.f, 0.f, 0.f, 0.f};

    if (fl) gemm_core<128, 128>(xb, D_, W, 0, D_, 1, D_, m0, n0, lds, acc);
    else    gemm_bf16<128, 128>(xb, D_, (const u16*)W, 0, D_, D_, m0, n0, lds, acc);

    EPI_SETUP
    __syncthreads();   // all waves done with staging LDS (needed for mode 0)
    const int wm = (wave >> 1) * 64, wn = (wave & 1) * 64;
    const int b = m0 >> 10, pos0 = m0 & 1023;
    const int dk0 = n0 >> 4;

    // phase 1: fragments -> LDS tile in destination order (swizzled)
    #pragma unroll
    for (int fm = 0; fm < 4; ++fm)
        #pragma unroll
        for (int fn = 0; fn < 4; ++fn) {
            int n_l = wn + fn * 16 + l15;
            float bz = bias[n0 + n_l];
            #pragma unroll
            for (int r = 0; r < 4; ++r) {
                int m_l = wm + fm * 16 + quad * 4 + r;
                u16 o = f2bf(acc[fm][fn][r] + bz);
                int off;
                if (mat == 0)
                    off = ((n_l & 15) << 10) + (m_l << 3) + (n_l >> 4);
                else if (mat == 1)
                    off = (((n_l & 15) * 8 + (m_l >> 4)) << 7)
                        + ((m_l & 15) << 3) + (n_l >> 4);
                else
                    off = (((n_l & 15) * 4 + (m_l >> 5)) << 8)
                        + (((m_l >> 3) & 3) << 6) + ((n_l >> 4) << 3) + (m_l & 7);
                lds[swz(off)] = o;
            }
        }
    __syncthreads();

    // phase 2: linear LDS reads -> coalesced 16B global stores
    #pragma unroll
    for (int j = 0; j < 8; ++j) {
        int flat = j * 2048 + tid * 8;
        bf16x8 v = *(const bf16x8*)&lds[swz(flat)];
        if (mat == 0) {
            int h = flat >> 10;
            int bh = b * 16 + h;
            size_t ga = (((size_t)(bh * 8 + (n0 >> 7)) * 1024 + pos0) << 3)
                      + (flat & 1023);
            *(bf16x8*)&qh[ga] = v;
        } else if (mat == 1) {
            int run = flat >> 7, h = run >> 3, g = run & 7;
            int bh = b * 16 + h;
            size_t base = (((size_t)bh * 64 + (pos0 >> 4) + g) << 10)
                        + ((size_t)(dk0 >> 5) << 9)
                        + ((size_t)((dk0 >> 3) & 3) << 7);
            *(bf16x8*)&kh[base + (flat & 127)] = v;
        } else {
            int chunk = flat >> 8, h = chunk >> 2, m5 = chunk & 3;
            int bh = b * 16 + h;
            size_t base = (((size_t)bh * 32 + (pos0 >> 5) + m5) << 11)
                        + ((size_t)(dk0 >> 4) << 9)
                        + ((size_t)((flat >> 6) & 3) << 7)
                        + ((size_t)(dk0 & 8) << 3);
            *(bf16x8*)&vt[base + (flat & 63)] = v;
        }
    }
}

// ---------------------------------------------------------------------------
// K2: flash attention. 4 WAVES PER BLOCK, all on the SAME head (bh):
// wave w handles q-tile q0 = qt*64 + w*16. The 4 waves read identical K/V
// fragments near-simultaneously -> L1 hits (4x fewer L2/global reads).
// Bijective XCD swizzle: lin -> swz so each XCD owns 8 heads (K/V working
// set 2 MB < 4 MB per-XCD L2). Barrier-free (waves independent).
// ---------------------------------------------------------------------------
__global__ __launch_bounds__(256) void k_flash(
    const u16* __restrict__ qh, const u16* __restrict__ kh,
    const u16* __restrict__ vt, u16* __restrict__ at, int alp)
{
    __shared__ __align__(16) u16 P[4 * 16 * 136];   // per-wave P tile / O staging

    const int lin = blockIdx.x;                     // 1024 blocks
    const int swzid = (lin & 7) * 128 + (lin >> 3); // XCD-chunked remap
    const int bh = swzid >> 4, b = bh >> 4, h = bh & 15;
    const int tid = threadIdx.x;
    const int wave = tid >> 6, lane = tid & 63;
    const int quad = lane >> 4, l15 = lane & 15;
    const int q0 = (swzid & 15) * 64 + wave * 16;
    u16* Pw = P + wave * 16 * 136;

    const u16* Kf = kh + ((size_t)bh << 16);
    const u16* Vf = vt + ((size_t)bh << 16);

    // Q frags from [bh][dkc][pos][dkl]: dkc = kk*4+quad
    bf16x8 qf[2];
    #pragma unroll
    for (int kk = 0; kk < 2; ++kk)
        qf[kk] = *(const bf16x8*)&qh[(((size_t)bh * 8 + kk * 4 + quad) * 1024
                                      + q0 + l15) * 8];

    f32x4 acc_o[4];
    #pragma unroll
    for (int j = 0; j < 4; ++j) acc_o[j] = f32x4{0.f, 0.f, 0.f, 0.f};
    float mrow[4], lrow[4];
    #pragma unroll
    for (int r = 0; r < 4; ++r) { mrow[r] = -1e30f; lrow[r] = 0.f; }

    const float c = 0.18033688011112042f;  // 0.125 * log2(e)

    #pragma unroll 2
    for (int mt = 0; mt < 8; ++mt) {
        f32x4 s[8];
        #pragma unroll
        for (int j = 0; j < 8; ++j) s[j] = f32x4{0.f, 0.f, 0.f, 0.f};
        #pragma unroll
        for (int kk = 0; kk < 2; ++kk) {
            bf16x8 kf[8];
            #pragma unroll
            for (int fn = 0; fn < 8; ++fn)
                kf[fn] = *(const bf16x8*)&Kf[((size_t)(mt * 8 + fn) << 10)
                                             + (kk << 9) + (quad << 7) + (l15 << 3)];
            #pragma unroll
            for (int fn = 0; fn < 8; ++fn)
                s[fn] = __builtin_amdgcn_mfma_f32_16x16x32_bf16(
                    qf[kk], kf[fn], s[fn], 0, 0, 0);
        }

        #pragma unroll
        for (int r = 0; r < 4; ++r) {
            float mx = s[0][r];
            #pragma unroll
            for (int fn = 1; fn < 8; ++fn) mx = fmaxf(mx, s[fn][r]);
            #pragma unroll
            for (int o = 1; o < 16; o <<= 1)
                mx = fmaxf(mx, __shfl_xor(mx, o, 64));
            float mn = fmaxf(mrow[r], mx);
            float al = EXP2((mrow[r] - mn) * c);
            float nmc = -mn * c;
            float rs = 0.f;
            #pragma unroll
            for (int fn = 0; fn < 8; ++fn) {
                float p = EXP2(fmaf(s[fn][r], c, nmc));
                s[fn][r] = p;
                rs += p;
            }
            #pragma unroll
            for (int o = 1; o < 16; o <<= 1)
                rs += __shfl_xor(rs, o, 64);
            lrow[r] = al * lrow[r] + rs;
            mrow[r] = mn;
            #pragma unroll
            for (int fn = 0; fn < 4; ++fn) acc_o[fn][r] *= al;
        }

        #pragma unroll
        for (int fn = 0; fn < 8; ++fn)
            #pragma unroll
            for (int r = 0; r < 4; ++r)
                Pw[(quad * 4 + r) * 136 + fn * 16 + l15] = f2bf(s[fn][r]);

        #pragma unroll
        for (int ks = 0; ks < 4; ++ks) {
            bf16x8 vf[4];
            #pragma unroll
            for (int fn = 0; fn < 4; ++fn)
                vf[fn] = *(const bf16x8*)&Vf[((size_t)(mt * 4 + ks) << 11)
                                             + (fn << 9) + (quad << 7) + (l15 << 3)];
            bf16x8 pf = *(bf16x8*)&Pw[l15 * 136 + ks * 32 + quad * 8];
            #pragma unroll
            for (int fn = 0; fn < 4; ++fn)
                acc_o[fn] = __builtin_amdgcn_mfma_f32_16x16x32_bf16(
                    pf, vf[fn], acc_o[fn], 0, 0, 0);
        }
    }

    float inv[4];
    #pragma unroll
    for (int r = 0; r < 4; ++r) inv[r] = 1.f / lrow[r];

    if (alp) {
        // O -> LDS [16][72] -> coalesced 16B stores into [b][pos][h*64+dk]
        #pragma unroll
        for (int fn = 0; fn < 4; ++fn)
            #pragma unroll
            for (int r = 0; r < 4; ++r)
                Pw[(quad * 4 + r) * 72 + fn * 16 + l15] = f2bf(acc_o[fn][r] * inv[r]);
        #pragma unroll
        for (int j = 0; j < 2; ++j) {
            int cidx = j * 64 + lane;
            int pos_l = cidx >> 3, dk8 = cidx & 7;
            bf16x8 v = *(const bf16x8*)&Pw[pos_l * 72 + dk8 * 8];
            *(bf16x8*)&at[((size_t)(b * N_ + q0 + pos_l)) * D_ + h * 64 + dk8 * 8] = v;
        }
    } else {
        #pragma unroll
        for (int r = 0; r < 4; ++r) {
            int pos = q0 + quad * 4 + r;
            #pragma unroll
            for (int fn = 0; fn < 4; ++fn) {
                int dk = fn * 16 + l15;
                at[((size_t)(b * N_ + pos)) * D_ + dk * 16 + h] =
                    f2bf(acc_o[fn][r] * inv[r]);
            }
        }
    }
}

// ---------------------------------------------------------------------------
// K3: merged = Wm . attn + bm.  MT=64,NT=128, grid (64,8).
// (alp modes: Wm is pre-permuted to match the at layout; code unchanged.)
// ---------------------------------------------------------------------------
__global__ __launch_bounds__(256) void k_merged(
    const u16* __restrict__ at, const void* __restrict__ Wm,
    const float* __restrict__ bm, int fl, u16* __restrict__ mg)
{
    __shared__ __align__(16) u16 lds[3 * (64 + 128) * 32];   // 36 KB
    int m0 = blockIdx.x * 64, n0 = blockIdx.y * 128;

    f32x4 acc[2][4];
    #pragma unroll
    for (int i = 0; i < 2; ++i)
        #pragma unroll
        for (int j = 0; j < 4; ++j) acc[i][j] = f32x4{0.f, 0.f, 0.f, 0.f};

    if (fl) gemm_core<64, 128>(at, D_, Wm, 0, D_, 1, D_, m0, n0, lds, acc);
    else    gemm_bf16<64, 128>(at, D_, (const u16*)Wm, 0, D_, D_, m0, n0, lds, acc);

    EPI_SETUP
    const int wm = (wave >> 1) * 32, wn = (wave & 1) * 64;
    #pragma unroll
    for (int fm = 0; fm < 2; ++fm)
        #pragma unroll
        for (int fn = 0; fn < 4; ++fn) {
            int n = n0 + wn + fn * 16 + l15;
            float bz = bm[n];
            #pragma unroll
            for (int r = 0; r < 4; ++r) {
                int m = m0 + wm + fm * 16 + quad * 4 + r;
                mg[(size_t)m * D_ + n] = f2bf(acc[fm][fn][r] + bz);
            }
        }
}

// ---------------------------------------------------------------------------
// K4: h2 = relu(BN(Wp1 . [merged; x] + bp1)): two accumulating K-passes.
// ---------------------------------------------------------------------------
__global__ __launch_bounds__(256) void k_p1(
    const u16* __restrict__ mg, const u16* __restrict__ xb,
    const void* __restrict__ Wp1, int fl,
    const float* __restrict__ bp1, const float* __restrict__ gam,
    const float* __restrict__ bet, const float* __restrict__ mu,
    const float* __restrict__ var, u16* __restrict__ h2)
{
    __shared__ __align__(16) u16 lds[3 * (128 + 128) * 32];   // 48 KB
    int m0 = blockIdx.x * 128, n0 = blockIdx.y * 128;

    f32x4 acc[4][4];
    #pragma unroll
    for (int i = 0; i < 4; ++i)
        #pragma unroll
        for (int j = 0; j < 4; ++j) acc[i][j] = f32x4{0.f, 0.f, 0.f, 0.f};

    if (fl) {
        gemm_core<128, 128>(mg, D_, Wp1, 0,    2048, 1, D_, m0, n0, lds, acc);
        gemm_core<128, 128>(xb, D_, Wp1, 1024, 2048, 1, D_, m0, n0, lds, acc);
    } else {
        gemm_bf16<128, 128>(mg, D_, (const u16*)Wp1, 0,    2048, D_, m0, n0, lds, acc);
        gemm_bf16<128, 128>(xb, D_, (const u16*)Wp1, 1024, 2048, D_, m0, n0, lds, acc);
    }

    EPI_SETUP
    const int wm = (wave >> 1) * 64, wn = (wave & 1) * 64;
    #pragma unroll
    for (int fm = 0; fm < 4; ++fm)
        #pragma unroll
        for (int fn = 0; fn < 4; ++fn) {
            int n = n0 + wn + fn * 16 + l15;
            float bz = bp1[n];
            float sc = gam[n] * rsqrtf(var[n] + 1e-5f);
            float mn = mu[n], be = bet[n];
            #pragma unroll
            for (int r = 0; r < 4; ++r) {
                int m = m0 + wm + fm * 16 + quad * 4 + r;
                float y = (acc[fm][fn][r] + bz - mn) * sc + be;
                h2[(size_t)m * 2048 + n] = f2bf(fmaxf(y, 0.f));
            }
        }
}

// ---------------------------------------------------------------------------
// K5: x += Wp2 . h2 + bp2.  MT=64,NT=128, grid (64,8).
// ---------------------------------------------------------------------------
__global__ __launch_bounds__(256) void k_p2(
    const u16* __restrict__ h2, const void* __restrict__ Wp2,
    const float* __restrict__ bp2, int fl,
    float* __restrict__ xf, u16* __restrict__ xb)
{
    __shared__ __align__(16) u16 lds[3 * (64 + 128) * 32];   // 36 KB
    int m0 = blockIdx.x * 64, n0 = blockIdx.y * 128;

    f32x4 acc[2][4];
    #pragma unroll
    for (int i = 0; i < 2; ++i)
        #pragma unroll
        for (int j = 0; j < 4; ++j) acc[i][j] = f32x4{0.f, 0.f, 0.f, 0.f};

    if (fl) gemm_core<64, 128>(h2, 2048, Wp2, 0, 2048, 1, 2048, m0, n0, lds, acc);
    else    gemm_bf16<64, 128>(h2, 2048, (const u16*)Wp2, 0, 2048, 2048, m0, n0, lds, acc);

    EPI_SETUP
    const int wm = (wave >> 1) * 32, wn = (wave & 1) * 64;
    #pragma unroll
    for (int fm = 0; fm < 2; ++fm)
        #pragma unroll
        for (int fn = 0; fn < 4; ++fn) {
            int n = n0 + wn + fn * 16 + l15;
            float bz = bp2[n];
            #pragma unroll
            for (int r = 0; r < 4; ++r) {
                int m = m0 + wm + fm * 16 + quad * 4 + r;
                size_t ad = (size_t)m * D_ + n;
                float nv = xf[ad] + acc[fm][fn][r] + bz;
                xf[ad] = nv;
                xb[ad] = f2bf(nv);
            }
        }
}

// K0: transpose motion (b,c,pos) fp32 -> xf/xb [b][pos][c]
__global__ __launch_bounds__(256) void k_tin(
    const float* __restrict__ mo, float* __restrict__ xf, u16* __restrict__ xb)
{
    __shared__ float t[32][33];
    int b = blockIdx.z;
    int p0 = blockIdx.x * 32, c0 = blockIdx.y * 32;
    int tx = threadIdx.x & 31, ty = threadIdx.x >> 5;
    const float* src = mo + ((size_t)b * D_ + c0) * N_ + p0;
    #pragma unroll
    for (int k = 0; k < 4; ++k)
        t[ty + k * 8][tx] = src[(size_t)(ty + k * 8) * N_ + tx];
    __syncthreads();
    size_t base = ((size_t)b * N_ + p0) * D_ + c0;
    #pragma unroll
    for (int k = 0; k < 4; ++k) {
        float v = t[tx][ty + k * 8];
        xf[base + (size_t)(ty + k * 8) * D_ + tx] = v;
        xb[base + (size_t)(ty + k * 8) * D_ + tx] = f2bf(v);
    }
}

// K6: transpose back, fp32 out
__global__ __launch_bounds__(256) void k_tout(
    const float* __restrict__ xf, float* __restrict__ out)
{
    __shared__ float t[32][33];
    int b = blockIdx.z;
    int c0 = blockIdx.x * 32, p0 = blockIdx.y * 32;
    int tx = threadIdx.x & 31, ty = threadIdx.x >> 5;
    const float* src = xf + ((size_t)b * N_ + p0) * D_ + c0;
    #pragma unroll
    for (int k = 0; k < 4; ++k)
        t[ty + k * 8][tx] = src[(size_t)(ty + k * 8) * D_ + tx];
    __syncthreads();
    float* dst = out + ((size_t)b * D_ + c0) * N_ + p0;
    #pragma unroll
    for (int k = 0; k < 4; ++k)
        dst[(size_t)(ty + k * 8) * N_ + tx] = t[tx][ty + k * 8];
}

extern "C" void kernel_launch(void* const* d_in, const int* in_sizes, int n_in,
                              void* d_out, int out_size, void* d_ws, size_t ws_size,
                              hipStream_t stream)
{
    const float* mo  = (const float*)d_in[0];
    const float* Wqf = (const float*)d_in[1];
    const float* bq  = (const float*)d_in[2];
    const float* Wkf = (const float*)d_in[3];
    const float* bk  = (const float*)d_in[4];
    const float* Wvf = (const float*)d_in[5];
    const float* bv  = (const float*)d_in[6];
    const float* Wmf = (const float*)d_in[7];
    const float* bm  = (const float*)d_in[8];
    const float* Wp1f= (const float*)d_in[9];
    const float* bp1 = (const float*)d_in[10];
    const float* gam = (const float*)d_in[11];
    const float* bet = (const float*)d_in[12];
    const float* mu  = (const float*)d_in[13];
    const float* var = (const float*)d_in[14];
    const float* Wp2f= (const float*)d_in[15];
    const float* bp2 = (const float*)d_in[16];

    char* ws = (char*)d_ws;
    float* xf = (float*)ws;                       //  0-16 MB fp32 residual
    u16* xb   = (u16*)(ws + (16ull << 20));       // 16-24
    u16* qh   = (u16*)(ws + (24ull << 20));       // 24-32 ; later mg
    u16* kh   = (u16*)(ws + (32ull << 20));       // 32-40 ; later h2 (spans kh+vt)
    u16* vt   = (u16*)(ws + (40ull << 20));       // 40-48
    u16* at   = (u16*)(ws + (48ull << 20));       // 48-56
    u16* mg   = qh;
    u16* h2   = kh;
    u16* wb   = (u16*)(ws + (56ull << 20));       // bf16 weight cache

    const size_t S1 = 1048576;      // one D*D matrix
    const size_t SP1 = 4194304;     // one 2048*2048
    const size_t SP2 = 2097152;     // one 1024*2048
    const size_t OQ = 0, OK4 = 4 * S1, OV = 8 * S1, OM = 12 * S1,
                 OP1 = 16 * S1, OP2 = OP1 + 4 * SP1;

    int mode;  // 2 = convert all layers (80MB), 1 = per-layer (20MB), 0 = fp32 direct
    if (ws_size >= (137ull << 20)) mode = 2;
    else if (ws_size >= (77ull << 20)) mode = 1;
    else mode = 0;
    const int fl = (mode == 0) ? 1 : 0;
    const int alp = (mode != 0);   // at layout permuted + Wm pre-permuted

    dim3 blk(256);
    if (mode == 2) {
        k_cvt<<<2048, blk, 0, stream>>>(Wqf,  wb + OQ,  524288);
        k_cvt<<<2048, blk, 0, stream>>>(Wkf,  wb + OK4, 524288);
        k_cvt<<<2048, blk, 0, stream>>>(Wvf,  wb + OV,  524288);
        for (int l = 0; l < 4; ++l)
            k_cvtperm<<<512, blk, 0, stream>>>(Wmf + l * S1, wb + OM + l * S1);
        k_cvt<<<8192, blk, 0, stream>>>(Wp1f, wb + OP1, 2097152);
        k_cvt<<<4096, blk, 0, stream>>>(Wp2f, wb + OP2, 1048576);
    }

    k_tin<<<dim3(32, 32, 4), blk, 0, stream>>>(mo, xf, xb);

    for (int l = 0; l < 4; ++l) {
        const void *pWq, *pWk, *pWv, *pWm, *pWp1, *pWp2;
        if (mode == 2) {
            pWq  = wb + OQ  + (size_t)l * S1;
            pWk  = wb + OK4 + (size_t)l * S1;
            pWv  = wb + OV  + (size_t)l * S1;
            pWm  = wb + OM  + (size_t)l * S1;
            pWp1 = wb + OP1 + (size_t)l * SP1;
            pWp2 = wb + OP2 + (size_t)l * SP2;
        } else if (mode == 1) {
            k_cvt<<<512,  blk, 0, stream>>>(Wqf  + l * S1,  wb,               131072);
            k_cvt<<<512,  blk, 0, stream>>>(Wkf  + l * S1,  wb + S1,          131072);
            k_cvt<<<512,  blk, 0, stream>>>(Wvf  + l * S1,  wb + 2 * S1,      131072);
            k_cvtperm<<<512, blk, 0, stream>>>(Wmf + l * S1, wb + 3 * S1);
            k_cvt<<<2048, blk, 0, stream>>>(Wp1f + l * SP1, wb + 4 * S1,      524288);
            k_cvt<<<1024, blk, 0, stream>>>(Wp2f + l * SP2, wb + 4 * S1 + SP1, 262144);
            pWq = wb; pWk = wb + S1; pWv = wb + 2 * S1; pWm = wb + 3 * S1;
            pWp1 = wb + 4 * S1; pWp2 = wb + 4 * S1 + SP1;
        } else {
            pWq  = Wqf  + l * S1;
            pWk  = Wkf  + l * S1;
            pWv  = Wvf  + l * S1;
            pWm  = Wmf  + l * S1;
            pWp1 = Wp1f + l * SP1;
            pWp2 = Wp2f + l * SP2;
        }

        k_qkv<<<dim3(32, 8, 3), blk, 0, stream>>>(
            xb, pWq, pWk, pWv, bq + l * D_, bk + l * D_, bv + l * D_, fl, qh, kh, vt);
        k_flash<<<dim3(1024), dim3(256), 0, stream>>>(qh, kh, vt, at, alp);
        k_merged<<<dim3(64, 8), blk, 0, stream>>>(at, pWm, bm + l * D_, fl, mg);
        k_p1<<<dim3(32, 16), blk, 0, stream>>>(
            mg, xb, pWp1, fl, bp1 + l * 2048, gam + l * 2048, bet + l * 2048,
            mu + l * 2048, var + l * 2048, h2);
        k_p2<<<dim3(64, 8), blk, 0, stream>>>(
            h2, pWp2, bp2 + l * D_, fl, xf, xb);
    }
    k_tout<<<dim3(32, 32, 4), blk, 0, stream>>>(xf, (float*)d_out);
}

// Round 6
// 989.235 us; speedup vs baseline: 1.3457x; 1.3457x over previous
//
#include <hip/hip_runtime.h>

typedef unsigned short u16;
typedef __attribute__((ext_vector_type(8))) short bf16x8;
typedef __attribute__((ext_vector_type(4))) float f32x4;

#define B_ 4
#define D_ 1024
#define N_ 1024
#define H_ 16
#define DK_ 64

__device__ inline float bf2f(u16 x) {
    union { unsigned u; float f; } c; c.u = ((unsigned)x) << 16; return c.f;
}
__device__ inline u16 f2bf(float f) {
    union { float f; unsigned u; } c; c.f = f;
    unsigned r = c.u + 0x7fff + ((c.u >> 16) & 1);
    return (u16)(r >> 16);
}

#if __has_builtin(__builtin_amdgcn_exp2f)
#define EXP2(x) __builtin_amdgcn_exp2f(x)
#else
#define EXP2(x) __expf((x) * 0.6931471805599453f)
#endif

// fl=1 -> storage fp32 (convert on load), fl=0 -> bf16
__device__ inline bf16x8 load8(const void* p, size_t idx, int fl) {
    if (!fl) return *(const bf16x8*)((const u16*)p + idx);
    const float* fp = (const float*)p + idx;
    f32x4 a = *(const f32x4*)fp;
    f32x4 b = *(const f32x4*)(fp + 4);
    bf16x8 r;
    #pragma unroll
    for (int j = 0; j < 4; ++j) {
        ((u16*)&r)[j]     = f2bf(a[j]);
        ((u16*)&r)[4 + j] = f2bf(b[j]);
    }
    return r;
}

// fp32 -> bf16 bulk convert, 8 elems/thread
__global__ __launch_bounds__(256) void k_cvt(
    const float* __restrict__ src, u16* __restrict__ dst, int n8)
{
    int i = blockIdx.x * 256 + threadIdx.x;
    if (i < n8) {
        const f32x4* s = (const f32x4*)src;
        f32x4 a = s[2 * i], b = s[2 * i + 1];
        bf16x8 r;
        #pragma unroll
        for (int j = 0; j < 4; ++j) {
            ((u16*)&r)[j]     = f2bf(a[j]);
            ((u16*)&r)[4 + j] = f2bf(b[j]);
        }
        ((bf16x8*)dst)[i] = r;
    }
}

// Wm permute+convert: dst[n][h*64+dk] = bf16(src[n][dk*16+h]).
// Matches at-layout [b][pos][h*64+dk] so k_merged needs no changes.
__global__ __launch_bounds__(256) void k_cvtperm(
    const float* __restrict__ src, u16* __restrict__ dst)
{
    int i = blockIdx.x * 256 + threadIdx.x;   // 131072 = 1024 rows * 128 chunks
    int n = i >> 7, c8 = i & 127;
    int h = c8 >> 3, dkb = (c8 & 7) * 8;
    bf16x8 r;
    #pragma unroll
    for (int e = 0; e < 8; ++e)
        ((u16*)&r)[e] = f2bf(src[(size_t)n * 1024 + (size_t)(dkb + e) * 16 + h]);
    *(bf16x8*)&dst[(size_t)n * 1024 + h * 64 + dkb] = r;
}

// ---------------------------------------------------------------------------
// global_load_lds direct-to-LDS staging.
// ---------------------------------------------------------------------------
__device__ __forceinline__ void gload16(const u16* g, u16* l) {
    __builtin_amdgcn_global_load_lds(
        (const __attribute__((address_space(1))) void*)g,
        (__attribute__((address_space(3))) void*)l, 16, 0, 0);
}

template<int ROWS>
__device__ __forceinline__ void stage_rows(const u16* __restrict__ g, int ld,
                                           int k0, u16* L, int wave)
{
    #pragma unroll
    for (int i = 0; i < ROWS / 64; ++i)
        gload16(g + (size_t)(i * 64) * ld + k0, L + i * 2048 + wave * 512);
}

template<int N>
__device__ __forceinline__ void waitcnt_vm() {
    if constexpr (N == 0)      asm volatile("s_waitcnt vmcnt(0)" ::: "memory");
    else if constexpr (N == 3) asm volatile("s_waitcnt vmcnt(3)" ::: "memory");
    else if constexpr (N == 4) asm volatile("s_waitcnt vmcnt(4)" ::: "memory");
    else if constexpr (N == 6) asm volatile("s_waitcnt vmcnt(6)" ::: "memory");
    else if constexpr (N == 8) asm volatile("s_waitcnt vmcnt(8)" ::: "memory");
}

// ---------------------------------------------------------------------------
// bf16 GEMM core: 3 LDS buffers, 2-deep prefetch, counted vmcnt.
// ---------------------------------------------------------------------------
template<int MT, int NT>
__device__ inline void gemm_bf16(const u16* __restrict__ A, int lda,
                                 const u16* __restrict__ Bt, size_t eoff,
                                 int ldb, int K, int m0, int n0,
                                 u16* lds, f32x4 acc[MT/32][NT/32])
{
    constexpr int FM = MT / 32, FN = NT / 32;
    constexpr int TSZ = (MT + NT) * 32;
    constexpr int NL  = MT / 64 + NT / 64;
    const int tid  = threadIdx.x;
    const int wave = tid >> 6, lane = tid & 63;
    const int quad = lane >> 4, l15 = lane & 15;
    const int wm = (wave >> 1) * (MT / 2);
    const int wn = (wave & 1) * (NT / 2);

    const u16* ga = A + (size_t)(m0 + (tid >> 2)) * lda + ((tid & 3) << 3);
    const u16* gb = Bt + eoff + (size_t)(n0 + (tid >> 2)) * ldb + ((tid & 3) << 3);

    stage_rows<MT>(ga, lda, 0, lds, wave);
    stage_rows<NT>(gb, ldb, 0, lds + MT * 32, wave);
    if (K > 32) {
        stage_rows<MT>(ga, lda, 32, lds + TSZ, wave);
        stage_rows<NT>(gb, ldb, 32, lds + TSZ + MT * 32, wave);
    }

    int b0 = 0;
    for (int k0 = 0; k0 < K - 32; k0 += 32) {
        waitcnt_vm<NL>();
        __builtin_amdgcn_s_barrier();

        const u16* La = lds + b0 * TSZ;
        const u16* Lb = La + MT * 32;
        bf16x8 af[FM], bv[FN];
        #pragma unroll
        for (int f = 0; f < FM; ++f)
            af[f] = *(const bf16x8*)&La[(wm + f * 16 + l15) * 32 + quad * 8];
        #pragma unroll
        for (int f = 0; f < FN; ++f)
            bv[f] = *(const bf16x8*)&Lb[(wn + f * 16 + l15) * 32 + quad * 8];

        if (k0 + 64 < K) {
            int b2 = b0 + 2; if (b2 >= 3) b2 -= 3;
            u16* Nx = lds + b2 * TSZ;
            stage_rows<MT>(ga, lda, k0 + 64, Nx, wave);
            stage_rows<NT>(gb, ldb, k0 + 64, Nx + MT * 32, wave);
        }

        #pragma unroll
        for (int fm = 0; fm < FM; ++fm)
            #pragma unroll
            for (int fn = 0; fn < FN; ++fn)
                acc[fm][fn] = __builtin_amdgcn_mfma_f32_16x16x32_bf16(
                    af[fm], bv[fn], acc[fm][fn], 0, 0, 0);

        b0 = (b0 == 2) ? 0 : b0 + 1;
    }

    waitcnt_vm<0>();
    __builtin_amdgcn_s_barrier();
    {
        const u16* La = lds + b0 * TSZ;
        const u16* Lb = La + MT * 32;
        bf16x8 af[FM], bv[FN];
        #pragma unroll
        for (int f = 0; f < FM; ++f)
            af[f] = *(const bf16x8*)&La[(wm + f * 16 + l15) * 32 + quad * 8];
        #pragma unroll
        for (int f = 0; f < FN; ++f)
            bv[f] = *(const bf16x8*)&Lb[(wn + f * 16 + l15) * 32 + quad * 8];
        #pragma unroll
        for (int fm = 0; fm < FM; ++fm)
            #pragma unroll
            for (int fn = 0; fn < FN; ++fn)
                acc[fm][fn] = __builtin_amdgcn_mfma_f32_16x16x32_bf16(
                    af[fm], bv[fn], acc[fm][fn], 0, 0, 0);
    }
    __syncthreads();
}

// ---------------------------------------------------------------------------
// fp32-weight fallback core (mode 0 only): reg-staged, padded LDS.
// ---------------------------------------------------------------------------
template<int MT, int NT>
__device__ inline void gemm_core(const u16* __restrict__ A, int lda,
                                 const void* __restrict__ Bt, size_t eoff,
                                 int ldb, int fl,
                                 int K, int m0, int n0,
                                 u16* lds, f32x4 acc[MT/32][NT/32])
{
    constexpr int FM = MT / 32, FN = NT / 32;
    constexpr int CA = MT * 4 / 256, CB = NT * 4 / 256;
    const int tid  = threadIdx.x;
    const int wave = tid >> 6, lane = tid & 63;
    const int quad = lane >> 4, l15 = lane & 15;
    const int wm = (wave >> 1) * (MT / 2);
    const int wn = (wave & 1) * (NT / 2);

    int arow[CA], acol[CA], brow[CB], bcol[CB];
    #pragma unroll
    for (int i = 0; i < CA; ++i) { int x = tid + i * 256; arow[i] = x >> 2; acol[i] = (x & 3) << 3; }
    #pragma unroll
    for (int i = 0; i < CB; ++i) { int x = tid + i * 256; brow[i] = x >> 2; bcol[i] = (x & 3) << 3; }

    bf16x8 pa[CA], pb[CB];
    #pragma unroll
    for (int i = 0; i < CA; ++i)
        pa[i] = *(const bf16x8*)(A + (size_t)(m0 + arow[i]) * lda + acol[i]);
    #pragma unroll
    for (int i = 0; i < CB; ++i)
        pb[i] = load8(Bt, eoff + (size_t)(n0 + brow[i]) * ldb + bcol[i], fl);

    int buf = 0;
    for (int k0 = 0; k0 < K; k0 += 32) {
        u16* La = lds + buf * ((MT + NT) * 40);
        u16* Lb = La + MT * 40;
        #pragma unroll
        for (int i = 0; i < CA; ++i) *(bf16x8*)&La[arow[i] * 40 + acol[i]] = pa[i];
        #pragma unroll
        for (int i = 0; i < CB; ++i) *(bf16x8*)&Lb[brow[i] * 40 + bcol[i]] = pb[i];
        __syncthreads();

        if (k0 + 32 < K) {
            #pragma unroll
            for (int i = 0; i < CA; ++i)
                pa[i] = *(const bf16x8*)(A + (size_t)(m0 + arow[i]) * lda + k0 + 32 + acol[i]);
            #pragma unroll
            for (int i = 0; i < CB; ++i)
                pb[i] = load8(Bt, eoff + (size_t)(n0 + brow[i]) * ldb + k0 + 32 + bcol[i], fl);
        }

        bf16x8 af[FM], bv[FN];
        #pragma unroll
        for (int f = 0; f < FM; ++f)
            af[f] = *(bf16x8*)&La[(wm + f * 16 + l15) * 40 + quad * 8];
        #pragma unroll
        for (int f = 0; f < FN; ++f)
            bv[f] = *(bf16x8*)&Lb[(wn + f * 16 + l15) * 40 + quad * 8];
        #pragma unroll
        for (int fm = 0; fm < FM; ++fm)
            #pragma unroll
            for (int fn = 0; fn < FN; ++fn)
                acc[fm][fn] = __builtin_amdgcn_mfma_f32_16x16x32_bf16(
                    af[fm], bv[fn], acc[fm][fn], 0, 0, 0);
        buf ^= 1;
    }
}

#define EPI_SETUP \
    const int tid = threadIdx.x; \
    const int wave = tid >> 6, lane = tid & 63; \
    const int quad = lane >> 4, l15 = lane & 15;

__device__ __forceinline__ int swz(int off) {
    return off ^ (((off >> 10) & 7) << 3);
}

// ---------------------------------------------------------------------------
// K1: QKV. z = mat (0=q,1=k,2=v). A = xb [4096][1024].
// q -> [bh][dkc=dk>>3][pos][dk&7]    (2KB-contiguous per block per h)
// k -> FRAGMENT layout: [bh][g=pos>>4][kk=dk>>5][quad=(dk>>3)&3][l15=pos&15][j=dk&7]
// v -> FRAGMENT layout: [bh][c=pos>>5][fn=dk>>4][quad=(pos>>3)&3][l15=dk&15][j=pos&7]
// Epilogue: acc -> LDS (dest-order, swizzled) -> linear b128 reads ->
// dwordx4 global stores (full 64B lines).
// ---------------------------------------------------------------------------
__global__ __launch_bounds__(256) void k_qkv(
    const u16* __restrict__ xb,
    const void* __restrict__ Wq, const void* __restrict__ Wk, const void* __restrict__ Wv,
    const float* __restrict__ bq, const float* __restrict__ bk, const float* __restrict__ bv,
    int fl, u16* __restrict__ qh, u16* __restrict__ kh, u16* __restrict__ vt)
{
    __shared__ __align__(16) u16 lds[3 * (128 + 128) * 32];   // 48 KB
    int mat = blockIdx.z;
    const void* W     = mat == 0 ? Wq : (mat == 1 ? Wk : Wv);
    const float* bias = mat == 0 ? bq : (mat == 1 ? bk : bv);
    int m0 = blockIdx.x * 128, n0 = blockIdx.y * 128;

    f32x4 acc[4][4];
    #pragma unroll
    for (int i = 0; i < 4; ++i)
        #pragma unroll
        for (int j = 0; j < 4; ++j) acc[i][j] = f32x4{0.f, 0.f, 0.f, 0.f};

    if (fl) gemm_core<128, 128>(xb, D_, W, 0, D_, 1, D_, m0, n0, lds, acc);
    else    gemm_bf16<128, 128>(xb, D_, (const u16*)W, 0, D_, D_, m0, n0, lds, acc);

    EPI_SETUP
    __syncthreads();   // all waves done with staging LDS (needed for mode 0)
    const int wm = (wave >> 1) * 64, wn = (wave & 1) * 64;
    const int b = m0 >> 10, pos0 = m0 & 1023;
    const int dk0 = n0 >> 4;

    // phase 1: fragments -> LDS tile in destination order (swizzled)
    #pragma unroll
    for (int fm = 0; fm < 4; ++fm)
        #pragma unroll
        for (int fn = 0; fn < 4; ++fn) {
            int n_l = wn + fn * 16 + l15;
            float bz = bias[n0 + n_l];
            #pragma unroll
            for (int r = 0; r < 4; ++r) {
                int m_l = wm + fm * 16 + quad * 4 + r;
                u16 o = f2bf(acc[fm][fn][r] + bz);
                int off;
                if (mat == 0)
                    off = ((n_l & 15) << 10) + (m_l << 3) + (n_l >> 4);
                else if (mat == 1)
                    off = (((n_l & 15) * 8 + (m_l >> 4)) << 7)
                        + ((m_l & 15) << 3) + (n_l >> 4);
                else
                    off = (((n_l & 15) * 4 + (m_l >> 5)) << 8)
                        + (((m_l >> 3) & 3) << 6) + ((n_l >> 4) << 3) + (m_l & 7);
                lds[swz(off)] = o;
            }
        }
    __syncthreads();

    // phase 2: linear LDS reads -> coalesced 16B global stores
    #pragma unroll
    for (int j = 0; j < 8; ++j) {
        int flat = j * 2048 + tid * 8;
        bf16x8 v = *(const bf16x8*)&lds[swz(flat)];
        if (mat == 0) {
            int h = flat >> 10;
            int bh = b * 16 + h;
            size_t ga = (((size_t)(bh * 8 + (n0 >> 7)) * 1024 + pos0) << 3)
                      + (flat & 1023);
            *(bf16x8*)&qh[ga] = v;
        } else if (mat == 1) {
            int run = flat >> 7, h = run >> 3, g = run & 7;
            int bh = b * 16 + h;
            size_t base = (((size_t)bh * 64 + (pos0 >> 4) + g) << 10)
                        + ((size_t)(dk0 >> 5) << 9)
                        + ((size_t)((dk0 >> 3) & 3) << 7);
            *(bf16x8*)&kh[base + (flat & 127)] = v;
        } else {
            int chunk = flat >> 8, h = chunk >> 2, m5 = chunk & 3;
            int bh = b * 16 + h;
            size_t base = (((size_t)bh * 32 + (pos0 >> 5) + m5) << 11)
                        + ((size_t)(dk0 >> 4) << 9)
                        + ((size_t)((flat >> 6) & 3) << 7)
                        + ((size_t)(dk0 & 8) << 3);
            *(bf16x8*)&vt[base + (flat & 63)] = v;
        }
    }
}

// ---------------------------------------------------------------------------
// K2: flash attention, ONE WAVE PER BLOCK (64 thr), 4096 blocks =
// 16 blocks/CU all-resident, zero tail. Bijective XCD swizzle:
// swzid = (lin&7)*512 + (lin>>3); XCD x (blocks lin==x mod 8) gets
// swzid in [512x,512x+512) = heads [8x,8x+8) -> K/V set 2MB < 4MB L2.
// ---------------------------------------------------------------------------
__global__ __launch_bounds__(64) void k_flash(
    const u16* __restrict__ qh, const u16* __restrict__ kh,
    const u16* __restrict__ vt, u16* __restrict__ at, int alp)
{
    __shared__ __align__(16) u16 P[16 * 136];   // P tile / O staging

    const int lin = blockIdx.x;                       // 4096 blocks
    const int swzid = (lin & 7) * 512 + (lin >> 3);   // bijective XCD remap
    const int bh = swzid >> 6, b = bh >> 4, h = bh & 15;
    const int lane = threadIdx.x;
    const int quad = lane >> 4, l15 = lane & 15;
    const int q0 = (swzid & 63) * 16;

    const u16* Kf = kh + ((size_t)bh << 16);
    const u16* Vf = vt + ((size_t)bh << 16);

    // Q frags from [bh][dkc][pos][dkl]: dkc = kk*4+quad
    bf16x8 qf[2];
    #pragma unroll
    for (int kk = 0; kk < 2; ++kk)
        qf[kk] = *(const bf16x8*)&qh[(((size_t)bh * 8 + kk * 4 + quad) * 1024
                                      + q0 + l15) * 8];

    f32x4 acc_o[4];
    #pragma unroll
    for (int j = 0; j < 4; ++j) acc_o[j] = f32x4{0.f, 0.f, 0.f, 0.f};
    float mrow[4], lrow[4];
    #pragma unroll
    for (int r = 0; r < 4; ++r) { mrow[r] = -1e30f; lrow[r] = 0.f; }

    const float c = 0.18033688011112042f;  // 0.125 * log2(e)

    #pragma unroll 2
    for (int mt = 0; mt < 8; ++mt) {
        f32x4 s[8];
        #pragma unroll
        for (int j = 0; j < 8; ++j) s[j] = f32x4{0.f, 0.f, 0.f, 0.f};
        #pragma unroll
        for (int kk = 0; kk < 2; ++kk) {
            bf16x8 kf[8];
            #pragma unroll
            for (int fn = 0; fn < 8; ++fn)
                kf[fn] = *(const bf16x8*)&Kf[((size_t)(mt * 8 + fn) << 10)
                                             + (kk << 9) + (quad << 7) + (l15 << 3)];
            #pragma unroll
            for (int fn = 0; fn < 8; ++fn)
                s[fn] = __builtin_amdgcn_mfma_f32_16x16x32_bf16(
                    qf[kk], kf[fn], s[fn], 0, 0, 0);
        }

        #pragma unroll
        for (int r = 0; r < 4; ++r) {
            float mx = s[0][r];
            #pragma unroll
            for (int fn = 1; fn < 8; ++fn) mx = fmaxf(mx, s[fn][r]);
            #pragma unroll
            for (int o = 1; o < 16; o <<= 1)
                mx = fmaxf(mx, __shfl_xor(mx, o, 64));
            float mn = fmaxf(mrow[r], mx);
            float al = EXP2((mrow[r] - mn) * c);
            float nmc = -mn * c;
            float rs = 0.f;
            #pragma unroll
            for (int fn = 0; fn < 8; ++fn) {
                float p = EXP2(fmaf(s[fn][r], c, nmc));
                s[fn][r] = p;
                rs += p;
            }
            #pragma unroll
            for (int o = 1; o < 16; o <<= 1)
                rs += __shfl_xor(rs, o, 64);
            lrow[r] = al * lrow[r] + rs;
            mrow[r] = mn;
            #pragma unroll
            for (int fn = 0; fn < 4; ++fn) acc_o[fn][r] *= al;
        }

        #pragma unroll
        for (int fn = 0; fn < 8; ++fn)
            #pragma unroll
            for (int r = 0; r < 4; ++r)
                P[(quad * 4 + r) * 136 + fn * 16 + l15] = f2bf(s[fn][r]);

        #pragma unroll
        for (int ks = 0; ks < 4; ++ks) {
            bf16x8 vf[4];
            #pragma unroll
            for (int fn = 0; fn < 4; ++fn)
                vf[fn] = *(const bf16x8*)&Vf[((size_t)(mt * 4 + ks) << 11)
                                             + (fn << 9) + (quad << 7) + (l15 << 3)];
            bf16x8 pf = *(bf16x8*)&P[l15 * 136 + ks * 32 + quad * 8];
            #pragma unroll
            for (int fn = 0; fn < 4; ++fn)
                acc_o[fn] = __builtin_amdgcn_mfma_f32_16x16x32_bf16(
                    pf, vf[fn], acc_o[fn], 0, 0, 0);
        }
    }

    float inv[4];
    #pragma unroll
    for (int r = 0; r < 4; ++r) inv[r] = 1.f / lrow[r];

    if (alp) {
        // O -> LDS [16][72] -> coalesced 16B stores into [b][pos][h*64+dk]
        #pragma unroll
        for (int fn = 0; fn < 4; ++fn)
            #pragma unroll
            for (int r = 0; r < 4; ++r)
                P[(quad * 4 + r) * 72 + fn * 16 + l15] = f2bf(acc_o[fn][r] * inv[r]);
        #pragma unroll
        for (int j = 0; j < 2; ++j) {
            int cidx = j * 64 + lane;
            int pos_l = cidx >> 3, dk8 = cidx & 7;
            bf16x8 v = *(const bf16x8*)&P[pos_l * 72 + dk8 * 8];
            *(bf16x8*)&at[((size_t)(b * N_ + q0 + pos_l)) * D_ + h * 64 + dk8 * 8] = v;
        }
    } else {
        #pragma unroll
        for (int r = 0; r < 4; ++r) {
            int pos = q0 + quad * 4 + r;
            #pragma unroll
            for (int fn = 0; fn < 4; ++fn) {
                int dk = fn * 16 + l15;
                at[((size_t)(b * N_ + pos)) * D_ + dk * 16 + h] =
                    f2bf(acc_o[fn][r] * inv[r]);
            }
        }
    }
}

// ---------------------------------------------------------------------------
// K3: merged = Wm . attn + bm.  MT=64,NT=128, grid (64,8).
// (alp modes: Wm is pre-permuted to match the at layout; code unchanged.)
// ---------------------------------------------------------------------------
__global__ __launch_bounds__(256) void k_merged(
    const u16* __restrict__ at, const void* __restrict__ Wm,
    const float* __restrict__ bm, int fl, u16* __restrict__ mg)
{
    __shared__ __align__(16) u16 lds[3 * (64 + 128) * 32];   // 36 KB
    int m0 = blockIdx.x * 64, n0 = blockIdx.y * 128;

    f32x4 acc[2][4];
    #pragma unroll
    for (int i = 0; i < 2; ++i)
        #pragma unroll
        for (int j = 0; j < 4; ++j) acc[i][j] = f32x4{0.f, 0.f, 0.f, 0.f};

    if (fl) gemm_core<64, 128>(at, D_, Wm, 0, D_, 1, D_, m0, n0, lds, acc);
    else    gemm_bf16<64, 128>(at, D_, (const u16*)Wm, 0, D_, D_, m0, n0, lds, acc);

    EPI_SETUP
    const int wm = (wave >> 1) * 32, wn = (wave & 1) * 64;
    #pragma unroll
    for (int fm = 0; fm < 2; ++fm)
        #pragma unroll
        for (int fn = 0; fn < 4; ++fn) {
            int n = n0 + wn + fn * 16 + l15;
            float bz = bm[n];
            #pragma unroll
            for (int r = 0; r < 4; ++r) {
                int m = m0 + wm + fm * 16 + quad * 4 + r;
                mg[(size_t)m * D_ + n] = f2bf(acc[fm][fn][r] + bz);
            }
        }
}

// ---------------------------------------------------------------------------
// K4: h2 = relu(BN(Wp1 . [merged; x] + bp1)): two accumulating K-passes.
// ---------------------------------------------------------------------------
__global__ __launch_bounds__(256) void k_p1(
    const u16* __restrict__ mg, const u16* __restrict__ xb,
    const void* __restrict__ Wp1, int fl,
    const float* __restrict__ bp1, const float* __restrict__ gam,
    const float* __restrict__ bet, const float* __restrict__ mu,
    const float* __restrict__ var, u16* __restrict__ h2)
{
    __shared__ __align__(16) u16 lds[3 * (128 + 128) * 32];   // 48 KB
    int m0 = blockIdx.x * 128, n0 = blockIdx.y * 128;

    f32x4 acc[4][4];
    #pragma unroll
    for (int i = 0; i < 4; ++i)
        #pragma unroll
        for (int j = 0; j < 4; ++j) acc[i][j] = f32x4{0.f, 0.f, 0.f, 0.f};

    if (fl) {
        gemm_core<128, 128>(mg, D_, Wp1, 0,    2048, 1, D_, m0, n0, lds, acc);
        gemm_core<128, 128>(xb, D_, Wp1, 1024, 2048, 1, D_, m0, n0, lds, acc);
    } else {
        gemm_bf16<128, 128>(mg, D_, (const u16*)Wp1, 0,    2048, D_, m0, n0, lds, acc);
        gemm_bf16<128, 128>(xb, D_, (const u16*)Wp1, 1024, 2048, D_, m0, n0, lds, acc);
    }

    EPI_SETUP
    const int wm = (wave >> 1) * 64, wn = (wave & 1) * 64;
    #pragma unroll
    for (int fm = 0; fm < 4; ++fm)
        #pragma unroll
        for (int fn = 0; fn < 4; ++fn) {
            int n = n0 + wn + fn * 16 + l15;
            float bz = bp1[n];
            float sc = gam[n] * rsqrtf(var[n] + 1e-5f);
            float mn = mu[n], be = bet[n];
            #pragma unroll
            for (int r = 0; r < 4; ++r) {
                int m = m0 + wm + fm * 16 + quad * 4 + r;
                float y = (acc[fm][fn][r] + bz - mn) * sc + be;
                h2[(size_t)m * 2048 + n] = f2bf(fmaxf(y, 0.f));
            }
        }
}

// ---------------------------------------------------------------------------
// K5: x += Wp2 . h2 + bp2.  MT=64,NT=128, grid (64,8).
// ---------------------------------------------------------------------------
__global__ __launch_bounds__(256) void k_p2(
    const u16* __restrict__ h2, const void* __restrict__ Wp2,
    const float* __restrict__ bp2, int fl,
    float* __restrict__ xf, u16* __restrict__ xb)
{
    __shared__ __align__(16) u16 lds[3 * (64 + 128) * 32];   // 36 KB
    int m0 = blockIdx.x * 64, n0 = blockIdx.y * 128;

    f32x4 acc[2][4];
    #pragma unroll
    for (int i = 0; i < 2; ++i)
        #pragma unroll
        for (int j = 0; j < 4; ++j) acc[i][j] = f32x4{0.f, 0.f, 0.f, 0.f};

    if (fl) gemm_core<64, 128>(h2, 2048, Wp2, 0, 2048, 1, 2048, m0, n0, lds, acc);
    else    gemm_bf16<64, 128>(h2, 2048, (const u16*)Wp2, 0, 2048, 2048, m0, n0, lds, acc);

    EPI_SETUP
    const int wm = (wave >> 1) * 32, wn = (wave & 1) * 64;
    #pragma unroll
    for (int fm = 0; fm < 2; ++fm)
        #pragma unroll
        for (int fn = 0; fn < 4; ++fn) {
            int n = n0 + wn + fn * 16 + l15;
            float bz = bp2[n];
            #pragma unroll
            for (int r = 0; r < 4; ++r) {
                int m = m0 + wm + fm * 16 + quad * 4 + r;
                size_t ad = (size_t)m * D_ + n;
                float nv = xf[ad] + acc[fm][fn][r] + bz;
                xf[ad] = nv;
                xb[ad] = f2bf(nv);
            }
        }
}

// K0: transpose motion (b,c,pos) fp32 -> xf/xb [b][pos][c]
__global__ __launch_bounds__(256) void k_tin(
    const float* __restrict__ mo, float* __restrict__ xf, u16* __restrict__ xb)
{
    __shared__ float t[32][33];
    int b = blockIdx.z;
    int p0 = blockIdx.x * 32, c0 = blockIdx.y * 32;
    int tx = threadIdx.x & 31, ty = threadIdx.x >> 5;
    const float* src = mo + ((size_t)b * D_ + c0) * N_ + p0;
    #pragma unroll
    for (int k = 0; k < 4; ++k)
        t[ty + k * 8][tx] = src[(size_t)(ty + k * 8) * N_ + tx];
    __syncthreads();
    size_t base = ((size_t)b * N_ + p0) * D_ + c0;
    #pragma unroll
    for (int k = 0; k < 4; ++k) {
        float v = t[tx][ty + k * 8];
        xf[base + (size_t)(ty + k * 8) * D_ + tx] = v;
        xb[base + (size_t)(ty + k * 8) * D_ + tx] = f2bf(v);
    }
}

// K6: transpose back, fp32 out
__global__ __launch_bounds__(256) void k_tout(
    const float* __restrict__ xf, float* __restrict__ out)
{
    __shared__ float t[32][33];
    int b = blockIdx.z;
    int c0 = blockIdx.x * 32, p0 = blockIdx.y * 32;
    int tx = threadIdx.x & 31, ty = threadIdx.x >> 5;
    const float* src = xf + ((size_t)b * N_ + p0) * D_ + c0;
    #pragma unroll
    for (int k = 0; k < 4; ++k)
        t[ty + k * 8][tx] = src[(size_t)(ty + k * 8) * D_ + tx];
    __syncthreads();
    float* dst = out + ((size_t)b * D_ + c0) * N_ + p0;
    #pragma unroll
    for (int k = 0; k < 4; ++k)
        dst[(size_t)(ty + k * 8) * N_ + tx] = t[tx][ty + k * 8];
}

extern "C" void kernel_launch(void* const* d_in, const int* in_sizes, int n_in,
                              void* d_out, int out_size, void* d_ws, size_t ws_size,
                              hipStream_t stream)
{
    const float* mo  = (const float*)d_in[0];
    const float* Wqf = (const float*)d_in[1];
    const float* bq  = (const float*)d_in[2];
    const float* Wkf = (const float*)d_in[3];
    const float* bk  = (const float*)d_in[4];
    const float* Wvf = (const float*)d_in[5];
    const float* bv  = (const float*)d_in[6];
    const float* Wmf = (const float*)d_in[7];
    const float* bm  = (const float*)d_in[8];
    const float* Wp1f= (const float*)d_in[9];
    const float* bp1 = (const float*)d_in[10];
    const float* gam = (const float*)d_in[11];
    const float* bet = (const float*)d_in[12];
    const float* mu  = (const float*)d_in[13];
    const float* var = (const float*)d_in[14];
    const float* Wp2f= (const float*)d_in[15];
    const float* bp2 = (const float*)d_in[16];

    char* ws = (char*)d_ws;
    float* xf = (float*)ws;                       //  0-16 MB fp32 residual
    u16* xb   = (u16*)(ws + (16ull << 20));       // 16-24
    u16* qh   = (u16*)(ws + (24ull << 20));       // 24-32 ; later mg
    u16* kh   = (u16*)(ws + (32ull << 20));       // 32-40 ; later h2 (spans kh+vt)
    u16* vt   = (u16*)(ws + (40ull << 20));       // 40-48
    u16* at   = (u16*)(ws + (48ull << 20));       // 48-56
    u16* mg   = qh;
    u16* h2   = kh;
    u16* wb   = (u16*)(ws + (56ull << 20));       // bf16 weight cache

    const size_t S1 = 1048576;      // one D*D matrix
    const size_t SP1 = 4194304;     // one 2048*2048
    const size_t SP2 = 2097152;     // one 1024*2048
    const size_t OQ = 0, OK4 = 4 * S1, OV = 8 * S1, OM = 12 * S1,
                 OP1 = 16 * S1, OP2 = OP1 + 4 * SP1;

    int mode;  // 2 = convert all layers (80MB), 1 = per-layer (20MB), 0 = fp32 direct
    if (ws_size >= (137ull << 20)) mode = 2;
    else if (ws_size >= (77ull << 20)) mode = 1;
    else mode = 0;
    const int fl = (mode == 0) ? 1 : 0;
    const int alp = (mode != 0);   // at layout permuted + Wm pre-permuted

    dim3 blk(256);
    if (mode == 2) {
        k_cvt<<<2048, blk, 0, stream>>>(Wqf,  wb + OQ,  524288);
        k_cvt<<<2048, blk, 0, stream>>>(Wkf,  wb + OK4, 524288);
        k_cvt<<<2048, blk, 0, stream>>>(Wvf,  wb + OV,  524288);
        for (int l = 0; l < 4; ++l)
            k_cvtperm<<<512, blk, 0, stream>>>(Wmf + l * S1, wb + OM + l * S1);
        k_cvt<<<8192, blk, 0, stream>>>(Wp1f, wb + OP1, 2097152);
        k_cvt<<<4096, blk, 0, stream>>>(Wp2f, wb + OP2, 1048576);
    }

    k_tin<<<dim3(32, 32, 4), blk, 0, stream>>>(mo, xf, xb);

    for (int l = 0; l < 4; ++l) {
        const void *pWq, *pWk, *pWv, *pWm, *pWp1, *pWp2;
        if (mode == 2) {
            pWq  = wb + OQ  + (size_t)l * S1;
            pWk  = wb + OK4 + (size_t)l * S1;
            pWv  = wb + OV  + (size_t)l * S1;
            pWm  = wb + OM  + (size_t)l * S1;
            pWp1 = wb + OP1 + (size_t)l * SP1;
            pWp2 = wb + OP2 + (size_t)l * SP2;
        } else if (mode == 1) {
            k_cvt<<<512,  blk, 0, stream>>>(Wqf  + l * S1,  wb,               131072);
            k_cvt<<<512,  blk, 0, stream>>>(Wkf  + l * S1,  wb + S1,          131072);
            k_cvt<<<512,  blk, 0, stream>>>(Wvf  + l * S1,  wb + 2 * S1,      131072);
            k_cvtperm<<<512, blk, 0, stream>>>(Wmf + l * S1, wb + 3 * S1);
            k_cvt<<<2048, blk, 0, stream>>>(Wp1f + l * SP1, wb + 4 * S1,      524288);
            k_cvt<<<1024, blk, 0, stream>>>(Wp2f + l * SP2, wb + 4 * S1 + SP1, 262144);
            pWq = wb; pWk = wb + S1; pWv = wb + 2 * S1; pWm = wb + 3 * S1;
            pWp1 = wb + 4 * S1; pWp2 = wb + 4 * S1 + SP1;
        } else {
            pWq  = Wqf  + l * S1;
            pWk  = Wkf  + l * S1;
            pWv  = Wvf  + l * S1;
            pWm  = Wmf  + l * S1;
            pWp1 = Wp1f + l * SP1;
            pWp2 = Wp2f + l * SP2;
        }

        k_qkv<<<dim3(32, 8, 3), blk, 0, stream>>>(
            xb, pWq, pWk, pWv, bq + l * D_, bk + l * D_, bv + l * D_, fl, qh, kh, vt);
        k_flash<<<dim3(4096), dim3(64), 0, stream>>>(qh, kh, vt, at, alp);
        k_merged<<<dim3(64, 8), blk, 0, stream>>>(at, pWm, bm + l * D_, fl, mg);
        k_p1<<<dim3(32, 16), blk, 0, stream>>>(
            mg, xb, pWp1, fl, bp1 + l * 2048, gam + l * 2048, bet + l * 2048,
            mu + l * 2048, var + l * 2048, h2);
        k_p2<<<dim3(64, 8), blk, 0, stream>>>(
            h2, pWp2, bp2 + l * D_, fl, xf, xb);
    }
    k_tout<<<dim3(32, 32, 4), blk, 0, stream>>>(xf, (float*)d_out);
}